// Round 1
// baseline (3846.699 us; speedup 1.0000x reference)
//
#include <hip/hip_runtime.h>
#include <stdint.h>

#define H 512
#define B_SZ 1024
#define T_WARM 256
#define NSTEPS 64
#define TOTAL_T (T_WARM + NSTEPS)

#define RPB 16          // rows per team
#define NTEAM 64        // B_SZ / RPB
#define NCG 4           // k-slice groups (blocks per team)
#define NBLK 256        // NTEAM * NCG
#define NTHR 512        // 8 waves
#define HSTR 136        // LDS row stride (ushorts) for [16][128] slice, 272B rows (16B-aligned)
#define MSG_U64 136     // 128 u64 partial tile + 8 u64 y-partials
#define MSGS_PER_PING (NTEAM * NCG * 8 * NCG)          // 8192
#define PING_U64 ((size_t)MSGS_PER_PING * MSG_U64)     // 1114112 u64

typedef __attribute__((ext_vector_type(8))) short bf16x8;
typedef __attribute__((ext_vector_type(4))) float f32x4;

static __device__ __forceinline__ ushort f2bf(float f) {
    uint32_t u = __builtin_bit_cast(uint32_t, f);
    u += 0x7FFFu + ((u >> 16) & 1u);
    return (ushort)(u >> 16);
}
static __device__ __forceinline__ float bf2f(ushort h) {
    uint32_t u = ((uint32_t)h) << 16;
    return __builtin_bit_cast(float, u);
}
static __device__ __forceinline__ uint64_t pack2f(float a, float b) {
    return (uint64_t)__builtin_bit_cast(uint32_t, a) |
           ((uint64_t)__builtin_bit_cast(uint32_t, b) << 32);
}
static __device__ __forceinline__ float lo_f(uint64_t u) {
    return __builtin_bit_cast(float, (uint32_t)u);
}
static __device__ __forceinline__ float hi_f(uint64_t u) {
    return __builtin_bit_cast(float, (uint32_t)(u >> 32));
}

__global__ void prep_kernel(const float* __restrict__ x,
                            const float* __restrict__ W_hh,
                            const float* __restrict__ b_ih,
                            const float* __restrict__ b_hh,
                            ushort* __restrict__ Wh, ushort* __restrict__ Wl,
                            float* __restrict__ bias, float* __restrict__ xT,
                            uint32_t* __restrict__ flags) {
    int i = blockIdx.x * NTHR + threadIdx.x;     // [0, 524288)
    if (i < 8192) flags[i] = 0u;                 // per-(team,ccg,wv,pcg) step counters
    if (i < H * H) {
        float w = W_hh[i];
        ushort hi = f2bf(w);
        Wh[i] = hi;
        Wl[i] = f2bf(w - bf2f(hi));
    }
    if (i < B_SZ * T_WARM) {
        int b = i & (B_SZ - 1), t = i >> 10;
        xT[t * B_SZ + b] = x[b * T_WARM + t];
    }
    if (i < H) bias[i] = b_ih[i] + b_hh[i];
}

// Partial-sum exchange RNN: block (team, cg) owns rows [16*team,+16) and h-cols
// [128*cg,+128). Its own output cols ARE its k-slice next step, so h never
// leaves the block; only f32 partial products (k-restricted GEMM outputs for
// the 3 peers' col ranges) are exchanged through agent-scope global memory.
__global__ __launch_bounds__(NTHR, 2)
void rnn_kernel(const float* __restrict__ xT,
                const float* __restrict__ W_ih,
                const float* __restrict__ b_fc_p,
                const float* __restrict__ W_fc,
                const ushort* __restrict__ Wh_g,
                const ushort* __restrict__ Wl_g,
                const float* __restrict__ bias_g,
                uint64_t* __restrict__ Pbuf,
                uint32_t* __restrict__ flags,
                float* __restrict__ out) {
    __shared__ __align__(16) ushort h_hi[2][RPB * HSTR];   // local slice, ping-pong
    __shared__ __align__(16) ushort h_lo[2][RPB * HSTR];

    const int tid  = threadIdx.x;
    const int bid  = blockIdx.x;
    const int team = bid & (NTEAM - 1);   // blocks {team, +64, +128, +192}: same bid%8 (XCD)
    const int cg   = bid >> 6;            // 0..3 — own col group == own k-slice
    const int row0 = team * RPB;
    const int col0 = cg * 128;            // global offset of local k-slice

    const int lane = tid & 63;
    const int wv   = tid >> 6;            // 0..7: 16-col tile index within each 128-col group
    const int n    = lane & 15, q = lane >> 4;

    // ---- register-resident weights: W[j = p*128+wv*16+n][k local], 4 tiles x 4 kt, hi+lo ----
    bf16x8 Bh[4][4], Bl[4][4];
    #pragma unroll
    for (int p = 0; p < 4; ++p) {
        const int jrow = p * 128 + wv * 16 + n;
        #pragma unroll
        for (int kt = 0; kt < 4; ++kt) {
            const int ko = col0 + kt * 32 + q * 8;
            Bh[p][kt] = *(const bf16x8*)(Wh_g + jrow * H + ko);
            Bl[p][kt] = *(const bf16x8*)(Wl_g + jrow * H + ko);
        }
    }
    const int jg = col0 + wv * 16 + n;        // this lane's own output col
    const float w_in = W_ih[jg];
    const float bj   = bias_g[jg];
    const float bfc  = b_fc_p[0];

    // message slots: [ping][team][consumer_cg][wv][producer_cg][136 u64]
    uint64_t* om[4];
    const uint64_t* im[4];
    #pragma unroll
    for (int p = 0; p < 4; ++p) {
        om[p] = Pbuf + ((((size_t)team * 4 + p)  * 8 + wv) * 4 + cg) * MSG_U64;
        im[p] = Pbuf + ((((size_t)team * 4 + cg) * 8 + wv) * 4 + p)  * MSG_U64;
    }
    uint32_t* const fst = flags + (((team * 4 + (lane & 3)) * 8 + wv) * 4) + cg;        // lane<4 stores
    const uint32_t* const fpl = flags + (((team * 4 + cg) * 8 + wv) * 4) + (lane & 3);  // lane<4 polls
    const bool flane = (lane < 4) && (lane != cg);

    // h(0) = 0
    for (int i = tid; i < RPB * HSTR; i += NTHR) { h_hi[0][i] = 0; h_lo[0][i] = 0; }
    __syncthreads();

    for (int t = 0; t < TOTAL_T; ++t) {
        const int pp = t & 1;
        const size_t po = pp ? PING_U64 : 0;
        const bool roll = (t >= T_WARM);

        f32x4 xq = {0.f, 0.f, 0.f, 0.f};
        if (!roll) xq = *(const f32x4*)(xT + t * B_SZ + row0 + q * 4);

        // ---- A fragments: own 16x128 slice from LDS (8 ds_read_b128) ----
        const ushort* hh = h_hi[pp];
        const ushort* hl = h_lo[pp];
        bf16x8 Ah[4], Al[4];
        #pragma unroll
        for (int kt = 0; kt < 4; ++kt) {
            Ah[kt] = *(const bf16x8*)(hh + n * HSTR + kt * 32 + q * 8);
            Al[kt] = *(const bf16x8*)(hl + n * HSTR + kt * 32 + q * 8);
        }

        // ---- remote tiles: 3 interleaved 12-deep chains, then store ASAP ----
        f32x4 acc[4];
        #pragma unroll
        for (int p = 0; p < 4; ++p) acc[p] = (f32x4){0.f, 0.f, 0.f, 0.f};
        #pragma unroll
        for (int kt = 0; kt < 4; ++kt) {
            const bf16x8 ah = Ah[kt], al = Al[kt];
            #pragma unroll
            for (int p = 0; p < 4; ++p) {
                if (p != cg) {
                    acc[p] = __builtin_amdgcn_mfma_f32_16x16x32_bf16(ah, Bh[p][kt], acc[p], 0, 0, 0);
                    acc[p] = __builtin_amdgcn_mfma_f32_16x16x32_bf16(al, Bh[p][kt], acc[p], 0, 0, 0);
                    acc[p] = __builtin_amdgcn_mfma_f32_16x16x32_bf16(ah, Bl[p][kt], acc[p], 0, 0, 0);
                }
            }
        }
        #pragma unroll
        for (int p = 0; p < 4; ++p) {
            if (p != cg) {
                uint64_t* m = om[p] + po;
                __hip_atomic_store(m + lane * 2,     pack2f(acc[p][0], acc[p][1]),
                                   __ATOMIC_RELAXED, __HIP_MEMORY_SCOPE_AGENT);
                __hip_atomic_store(m + lane * 2 + 1, pack2f(acc[p][2], acc[p][3]),
                                   __ATOMIC_RELAXED, __HIP_MEMORY_SCOPE_AGENT);
            }
        }

        // ---- rollout: block-partial y from A-frags (VALU), appended to messages ----
        float yv = 0.f;
        if (roll) {
            #pragma unroll
            for (int kt = 0; kt < 4; ++kt) {
                const float* wf = W_fc + col0 + kt * 32 + q * 8;
                f32x4 w0 = *(const f32x4*)(wf);
                f32x4 w1 = *(const f32x4*)(wf + 4);
                #pragma unroll
                for (int j = 0; j < 4; ++j) {
                    yv += (bf2f((ushort)Ah[kt][j])     + bf2f((ushort)Al[kt][j]))     * w0[j];
                    yv += (bf2f((ushort)Ah[kt][j + 4]) + bf2f((ushort)Al[kt][j + 4])) * w1[j];
                }
            }
            yv += __shfl_xor(yv, 16);
            yv += __shfl_xor(yv, 32);          // all lanes: y-partial for row n
            if (lane < 16) {
                #pragma unroll
                for (int p = 0; p < 4; ++p) {
                    if (p != cg) {
                        uint32_t* yp = (uint32_t*)(om[p] + po + 128);
                        __hip_atomic_store(yp + lane, __builtin_bit_cast(uint32_t, yv),
                                           __ATOMIC_RELAXED, __HIP_MEMORY_SCOPE_AGENT);
                    }
                }
            }
        }

        // ---- publish: drain this wave's stores, then per-wave flags ----
        asm volatile("s_waitcnt vmcnt(0)" ::: "memory");
        if (flane)
            __hip_atomic_store(fst, (uint32_t)(t + 1),
                               __ATOMIC_RELAXED, __HIP_MEMORY_SCOPE_AGENT);

        // ---- own tile (2 chains) — overlaps peers' store latency ----
        f32x4 o0 = {0.f, 0.f, 0.f, 0.f}, o1 = {0.f, 0.f, 0.f, 0.f};
        #pragma unroll
        for (int p = 0; p < 4; ++p) {
            if (p == cg) {
                #pragma unroll
                for (int kt = 0; kt < 2; ++kt) {
                    o0 = __builtin_amdgcn_mfma_f32_16x16x32_bf16(Ah[kt],     Bh[p][kt],     o0, 0, 0, 0);
                    o0 = __builtin_amdgcn_mfma_f32_16x16x32_bf16(Al[kt],     Bh[p][kt],     o0, 0, 0, 0);
                    o0 = __builtin_amdgcn_mfma_f32_16x16x32_bf16(Ah[kt],     Bl[p][kt],     o0, 0, 0, 0);
                    o1 = __builtin_amdgcn_mfma_f32_16x16x32_bf16(Ah[kt + 2], Bh[p][kt + 2], o1, 0, 0, 0);
                    o1 = __builtin_amdgcn_mfma_f32_16x16x32_bf16(Al[kt + 2], Bh[p][kt + 2], o1, 0, 0, 0);
                    o1 = __builtin_amdgcn_mfma_f32_16x16x32_bf16(Ah[kt + 2], Bl[p][kt + 2], o1, 0, 0, 0);
                }
            }
        }

        // ---- wait for the 3 incoming partial tiles ----
        {
            const uint32_t need = (uint32_t)(t + 1);
            while (true) {
                uint32_t f = 0xFFFFFFFFu;
                if (flane)
                    f = __hip_atomic_load(fpl, __ATOMIC_RELAXED, __HIP_MEMORY_SCOPE_AGENT);
                if (__all((int)(f >= need))) break;
                __builtin_amdgcn_s_sleep(1);
            }
        }

        // ---- gather + reduce ----
        f32x4 rsum = {0.f, 0.f, 0.f, 0.f};
        float ypeer = 0.f;
        #pragma unroll
        for (int p = 0; p < 4; ++p) {
            if (p != cg) {
                const uint64_t* m = im[p] + po;
                uint64_t a = __hip_atomic_load(m + lane * 2,     __ATOMIC_RELAXED, __HIP_MEMORY_SCOPE_AGENT);
                uint64_t b = __hip_atomic_load(m + lane * 2 + 1, __ATOMIC_RELAXED, __HIP_MEMORY_SCOPE_AGENT);
                rsum[0] += lo_f(a); rsum[1] += hi_f(a);
                rsum[2] += lo_f(b); rsum[3] += hi_f(b);
                if (roll) {
                    uint32_t yw = __hip_atomic_load((const uint32_t*)(m + 128) + n,
                                                    __ATOMIC_RELAXED, __HIP_MEMORY_SCOPE_AGENT);
                    ypeer += __builtin_bit_cast(float, yw);
                }
            }
        }

        // ---- epilogue: v = own + Σpeers + s*w_in + bias, relu, split, stage locally ----
        float sv[4];
        if (roll) {
            const float yf = yv + ypeer + bfc;             // y for row n, all lanes
            if (cg == 0 && wv == 0 && lane < 16)
                out[(row0 + lane) * NSTEPS + (t - T_WARM)] = yf;
            #pragma unroll
            for (int i = 0; i < 4; ++i) sv[i] = __shfl(yf, q * 4 + i);
        } else {
            #pragma unroll
            for (int i = 0; i < 4; ++i) sv[i] = xq[i];
        }
        ushort* dh = h_hi[pp ^ 1];
        ushort* dl = h_lo[pp ^ 1];
        const int jl = wv * 16 + n;                        // local k-index next step
        #pragma unroll
        for (int i = 0; i < 4; ++i) {
            const int m = q * 4 + i;                       // C/D: row = quad*4+reg, col = lane&15
            float v = o0[i] + o1[i] + rsum[i] + sv[i] * w_in + bj;
            v = fmaxf(v, 0.f);
            const ushort hb = f2bf(v);
            dh[m * HSTR + jl] = hb;
            dl[m * HSTR + jl] = f2bf(v - bf2f(hb));
        }
        __syncthreads();   // orders h[pp^1] writes vs next step's reads
    }
}

extern "C" void kernel_launch(void* const* d_in, const int* in_sizes, int n_in,
                              void* d_out, int out_size, void* d_ws, size_t ws_size,
                              hipStream_t stream) {
    const float* x    = (const float*)d_in[0];
    const float* W_ih = (const float*)d_in[1];
    const float* W_hh = (const float*)d_in[2];
    const float* b_ih = (const float*)d_in[3];
    const float* b_hh = (const float*)d_in[4];
    const float* W_fc = (const float*)d_in[5];
    const float* b_fc = (const float*)d_in[6];
    float* out = (float*)d_out;

    // ws carve (bytes): Wh 512K | Wl 512K | bias 4K | xT 1M | flags 32K | Pbuf 17.8M  (~20 MB)
    uint8_t* w = (uint8_t*)d_ws;
    ushort*   Wh    = (ushort*)(w);
    ushort*   Wl    = (ushort*)(w + 524288);
    float*    bias  = (float*)(w + 1048576);
    float*    xT    = (float*)(w + 1052672);
    uint32_t* flags = (uint32_t*)(w + 2101248);
    uint64_t* Pbuf  = (uint64_t*)(w + 2134016);

    prep_kernel<<<1024, NTHR, 0, stream>>>(x, W_hh, b_ih, b_hh, Wh, Wl, bias, xT, flags);
    rnn_kernel<<<NBLK, NTHR, 0, stream>>>(xT, W_ih, b_fc, W_fc, Wh, Wl, bias, Pbuf, flags, out);
}

// Round 2
// 2058.079 us; speedup vs baseline: 1.8691x; 1.8691x over previous
//
#include <hip/hip_runtime.h>
#include <stdint.h>

#define H 512
#define B_SZ 1024
#define T_WARM 256
#define NSTEPS 64
#define TOTAL_T (T_WARM + NSTEPS)

#define RPB 16          // rows per team
#define NTEAM 64        // B_SZ / RPB
#define NCG 4           // col/k-slice groups (blocks per team)
#define NBLK 256        // NTEAM * NCG == CU count, 1 block/CU
#define NTHR 512        // 8 waves = 4 col-groups x 2 k-halves
#define HSTR 536        // LDS h row stride in ushorts (1072 B; word-stride 268 = 12 mod 32)
#define REDS 20         // partial-reduce row stride in words (2-way-free banks)

typedef __attribute__((ext_vector_type(8))) short bf16x8;
typedef __attribute__((ext_vector_type(4))) float f32x4;

static __device__ __forceinline__ ushort f2bf(float f) {
    uint32_t u = __builtin_bit_cast(uint32_t, f);
    u += 0x7FFFu + ((u >> 16) & 1u);
    return (ushort)(u >> 16);
}
static __device__ __forceinline__ float bf2f(ushort h) {
    uint32_t u = ((uint32_t)h) << 16;
    return __builtin_bit_cast(float, u);
}

__global__ void prep_kernel(const float* __restrict__ x,
                            const float* __restrict__ W_hh,
                            const float* __restrict__ b_ih,
                            const float* __restrict__ b_hh,
                            ushort* __restrict__ Wh, ushort* __restrict__ Wl,
                            float* __restrict__ bias, float* __restrict__ xT,
                            uint32_t* __restrict__ Hb0, uint32_t* __restrict__ flags) {
    int i = blockIdx.x * NTHR + threadIdx.x;     // [0, 524288)
    Hb0[i] = 0u;                                  // h(0) = 0 (packed hi|lo)
    if (i < 4096) flags[i] = 0u;                  // per-(team,cg,wave) step counters
    if (i < H * H) {
        float w = W_hh[i];
        ushort hi = f2bf(w);
        Wh[i] = hi;
        Wl[i] = f2bf(w - bf2f(hi));
    }
    if (i < B_SZ * T_WARM) {
        int b = i & (B_SZ - 1), t = i >> 10;
        xT[t * B_SZ + b] = x[b * T_WARM + t];
    }
    if (i < H) bias[i] = b_ih[i] + b_hh[i];
}

// Team of 4 same-XCD blocks shares 16 rows; block cg owns cols [128cg,+128).
// 8 waves = 4 col-groups (g) x 2 k-halves (kh): wave computes 32 cols over K=256.
// kh-pairs reduce via LDS; kh0 waves write own cols directly into next LDS h
// buffer (no tr scratch, no barrier-I) and publish per-wave flags after their
// own vmcnt drain.
__global__ __launch_bounds__(NTHR, 1)
void rnn_kernel(const float* __restrict__ xT,
                const float* __restrict__ W_ih,
                const float* __restrict__ b_fc_p,
                const float* __restrict__ W_fc,
                const ushort* __restrict__ Wh_g,
                const ushort* __restrict__ Wl_g,
                const float* __restrict__ bias_g,
                uint32_t* __restrict__ Hb0, uint32_t* __restrict__ Hb1,
                uint32_t* __restrict__ flags,
                float* __restrict__ out) {
    __shared__ __align__(16) ushort h_hi[2][RPB * HSTR];   // ping-pong hi
    __shared__ __align__(16) ushort h_lo[2][RPB * HSTR];   // ping-pong lo
    __shared__ __align__(16) float  red_s[8 * RPB * REDS]; // kh1 partials, 8 regions
    __shared__ __align__(16) float  w_fc_s[H];
    __shared__ float sy2[RPB];                             // kh1 y-partials

    const int tid  = threadIdx.x;
    const int bid  = blockIdx.x;
    const int team = bid & (NTEAM - 1);   // blocks {team,+64,+128,+192}: same XCD
    const int cg   = bid >> 6;            // 0..3
    const int row0 = team * RPB;
    const int col0 = cg * 128;

    const int lane = tid & 63;
    const int wv   = tid >> 6;            // 0..7
    const int g    = wv & 3;              // col-group: cols [col0+32g, +32)
    const int kh   = wv >> 2;             // k-half: k in [256kh, +256)
    const int n    = lane & 15, q = lane >> 4;

    w_fc_s[tid] = W_fc[tid];
    for (int i = tid; i < RPB * HSTR; i += NTHR) {
        h_hi[0][i] = 0; h_lo[0][i] = 0;
        h_hi[1][i] = 0; h_lo[1][i] = 0;
    }

    // ---- register-resident weights: 2 col-tiles x 8 kt, hi+lo = 128 VGPRs ----
    bf16x8 Bh[2][8], Bl[2][8];
    #pragma unroll
    for (int tt = 0; tt < 2; ++tt) {
        const int j = col0 + g * 32 + tt * 16 + n;
        #pragma unroll
        for (int kt = 0; kt < 8; ++kt) {
            const int ko = kh * 256 + kt * 32 + q * 8;
            Bh[tt][kt] = *(const bf16x8*)(Wh_g + j * H + ko);
            Bl[tt][kt] = *(const bf16x8*)(Wl_g + j * H + ko);
        }
    }
    float wi[2], bj[2];
    #pragma unroll
    for (int tt = 0; tt < 2; ++tt) {
        const int j = col0 + g * 32 + tt * 16 + n;
        wi[tt] = W_ih[j];
        bj[tt] = bias_g[j];
    }
    const float bfc = b_fc_p[0];

    // staging: wave wv stages 64-col slice s=wv unless produced by own block
    const int s = wv;
    const bool remote = (s >> 1) != cg;
    const uint64_t* pollp =
        (const uint64_t*)(flags + (team * 4 + (s >> 1)) * 16 + (s & 1) * 2);
    uint32_t* const myflag = flags + (team * 4 + cg) * 16 + g;   // kh0 publishes

    __syncthreads();

    for (int t = 0; t < TOTAL_T; ++t) {
        const int pp = t & 1;
        const bool roll = (t >= T_WARM);

        f32x4 xq = {0.f, 0.f, 0.f, 0.f};
        if (!roll && kh == 0)
            xq = *(const f32x4*)(xT + t * B_SZ + row0 + q * 4);

        // ---- ACQ: remote slices via poll + L2 load + unpack into LDS ----
        if (remote) {
            if (t > 0) {
                const uint32_t need = (uint32_t)t;
                while (true) {
                    uint64_t f = __hip_atomic_load(pollp, __ATOMIC_RELAXED,
                                                   __HIP_MEMORY_SCOPE_AGENT);
                    if ((uint32_t)f >= need && (uint32_t)(f >> 32) >= need) break;
                    __builtin_amdgcn_s_sleep(1);
                }
            }
            const uint32_t* hb = (t & 1) ? Hb1 : Hb0;
            const uint64_t* src = (const uint64_t*)hb;
            uint64_t tmp[8];
            #pragma unroll
            for (int it = 0; it < 8; ++it) {
                int idx = it * 64 + lane;            // r = idx>>5, c = idx&31
                int r = idx >> 5, c = idx & 31;
                tmp[it] = __hip_atomic_load(src + ((row0 + r) * 256 + s * 32 + c),
                                            __ATOMIC_RELAXED, __HIP_MEMORY_SCOPE_AGENT);
            }
            ushort* hhb = h_hi[pp];
            ushort* hlb = h_lo[pp];
            #pragma unroll
            for (int it = 0; it < 8; ++it) {
                int idx = it * 64 + lane;
                int r = idx >> 5, c = idx & 31;
                int k = s * 64 + c * 2;
                uint64_t u = tmp[it];
                uint32_t w0 = (uint32_t)u, w1 = (uint32_t)(u >> 32);
                uint32_t hw = (w0 >> 16) | (w1 & 0xFFFF0000u);
                uint32_t lw = (w0 & 0xFFFFu) | (w1 << 16);
                *(uint32_t*)(&hhb[r * HSTR + k]) = hw;
                *(uint32_t*)(&hlb[r * HSTR + k]) = lw;
            }
        }
        __syncthreads();   // E: all slices staged (self cols written last epilogue)

        // ---- A fragments: own k-half, 16 ds_read_b128 ----
        const ushort* ha = h_hi[pp] + n * HSTR + kh * 256 + q * 8;
        const ushort* la = h_lo[pp] + n * HSTR + kh * 256 + q * 8;
        bf16x8 Ah[8], Al[8];
        #pragma unroll
        for (int kt = 0; kt < 8; ++kt) {
            Ah[kt] = *(const bf16x8*)(ha + kt * 32);
            Al[kt] = *(const bf16x8*)(la + kt * 32);
        }

        // ---- MFMA: 2 col-tiles x 8 kt x 3 terms ----
        f32x4 a0 = {0.f, 0.f, 0.f, 0.f}, a1 = {0.f, 0.f, 0.f, 0.f};
        #pragma unroll
        for (int kt = 0; kt < 8; ++kt) {
            const bf16x8 ah = Ah[kt], al = Al[kt];
            a0 = __builtin_amdgcn_mfma_f32_16x16x32_bf16(ah, Bh[0][kt], a0, 0, 0, 0);
            a1 = __builtin_amdgcn_mfma_f32_16x16x32_bf16(ah, Bh[1][kt], a1, 0, 0, 0);
            a0 = __builtin_amdgcn_mfma_f32_16x16x32_bf16(al, Bh[0][kt], a0, 0, 0, 0);
            a1 = __builtin_amdgcn_mfma_f32_16x16x32_bf16(al, Bh[1][kt], a1, 0, 0, 0);
            a0 = __builtin_amdgcn_mfma_f32_16x16x32_bf16(ah, Bl[0][kt], a0, 0, 0, 0);
            a1 = __builtin_amdgcn_mfma_f32_16x16x32_bf16(ah, Bl[1][kt], a1, 0, 0, 0);
        }

        // ---- y-partial from A-frags (roll only): wfc via LDS broadcast ----
        float yp = 0.f;
        if (roll) {
            #pragma unroll
            for (int kt = 0; kt < 8; ++kt) {
                const float* wf = &w_fc_s[kh * 256 + kt * 32 + q * 8];
                f32x4 w0 = *(const f32x4*)wf;
                f32x4 w1 = *(const f32x4*)(wf + 4);
                #pragma unroll
                for (int j = 0; j < 4; ++j) {
                    yp += (bf2f((ushort)Ah[kt][j])     + bf2f((ushort)Al[kt][j]))     * w0[j];
                    yp += (bf2f((ushort)Ah[kt][j + 4]) + bf2f((ushort)Al[kt][j + 4])) * w1[j];
                }
            }
            yp += __shfl_xor(yp, 16);
            yp += __shfl_xor(yp, 32);      // all lanes: row-n partial for this kh
        }

        // ---- kh1: deposit partials (banks: n + 16(q&1), 2-way free) ----
        if (kh == 1) {
            float* r0 = &red_s[(g * 2 + 0) * RPB * REDS];
            float* r1 = &red_s[(g * 2 + 1) * RPB * REDS];
            #pragma unroll
            for (int i = 0; i < 4; ++i) {
                const int m = q * 4 + i;
                r0[m * REDS + n] = a0[i];
                r1[m * REDS + n] = a1[i];
            }
            if (roll && g == 0 && q == 0) sy2[n] = yp;
        }
        __syncthreads();   // R: partials visible

        // ---- kh0: combine, epilogue, publish ----
        if (kh == 0) {
            const float* r0 = &red_s[(g * 2 + 0) * RPB * REDS];
            const float* r1 = &red_s[(g * 2 + 1) * RPB * REDS];
            float yfin = 0.f;
            if (roll) {
                yfin = yp + sy2[n] + bfc;
                if (g == 0 && q == 0)
                    out[(row0 + n) * NSTEPS + (t - T_WARM)] = yfin;
            }
            ushort* dh = h_hi[pp ^ 1];
            ushort* dl = h_lo[pp ^ 1];
            uint32_t* hbn = (t & 1) ? Hb0 : Hb1;
            #pragma unroll
            for (int i = 0; i < 4; ++i) {
                const int m = q * 4 + i;           // C/D: row = quad*4+reg, col = n
                const float sv = roll ? __shfl(yfin, m) : xq[i];
                #pragma unroll
                for (int tt = 0; tt < 2; ++tt) {
                    const float accv = tt ? a1[i] : a0[i];
                    const float redv = tt ? r1[m * REDS + n] : r0[m * REDS + n];
                    float v = accv + redv + sv * wi[tt] + bj[tt];
                    v = fmaxf(v, 0.f);
                    const ushort hb16 = f2bf(v);
                    const ushort lb16 = f2bf(v - bf2f(hb16));
                    const uint32_t pk = ((uint32_t)hb16 << 16) | lb16;
                    const int jcol = col0 + g * 32 + tt * 16 + n;
                    __hip_atomic_store(hbn + (row0 + m) * H + jcol, pk,
                                       __ATOMIC_RELAXED, __HIP_MEMORY_SCOPE_AGENT);
                    // self cols direct into next LDS buffer (shfl-packed u32)
                    const uint32_t nb = __shfl_xor(pk, 1);
                    if ((n & 1) == 0) {
                        const uint32_t hiw = (pk >> 16)      | (nb & 0xFFFF0000u);
                        const uint32_t low = (pk & 0xFFFFu)  | (nb << 16);
                        *(uint32_t*)(&dh[m * HSTR + jcol]) = hiw;
                        *(uint32_t*)(&dl[m * HSTR + jcol]) = low;
                    }
                }
            }
            asm volatile("s_waitcnt vmcnt(0)" ::: "memory");
            if (lane == 0)
                __hip_atomic_store(myflag, (uint32_t)(t + 1),
                                   __ATOMIC_RELAXED, __HIP_MEMORY_SCOPE_AGENT);
        }
        // no barrier-I: next step's E orders LDS; flags order globals
    }
}

extern "C" void kernel_launch(void* const* d_in, const int* in_sizes, int n_in,
                              void* d_out, int out_size, void* d_ws, size_t ws_size,
                              hipStream_t stream) {
    const float* x    = (const float*)d_in[0];
    const float* W_ih = (const float*)d_in[1];
    const float* W_hh = (const float*)d_in[2];
    const float* b_ih = (const float*)d_in[3];
    const float* b_hh = (const float*)d_in[4];
    const float* W_fc = (const float*)d_in[5];
    const float* b_fc = (const float*)d_in[6];
    float* out = (float*)d_out;

    // ws carve (bytes): Wh 512K | Wl 512K | bias 4K | xT 1M | Hb0 2M | Hb1 2M | flags 16K
    uint8_t* w = (uint8_t*)d_ws;
    ushort*   Wh    = (ushort*)(w);
    ushort*   Wl    = (ushort*)(w + 524288);
    float*    bias  = (float*)(w + 1048576);
    float*    xT    = (float*)(w + 1052672);
    uint32_t* Hb0   = (uint32_t*)(w + 2101248);
    uint32_t* Hb1   = (uint32_t*)(w + 4198400);
    uint32_t* flags = (uint32_t*)(w + 6295552);

    prep_kernel<<<1024, NTHR, 0, stream>>>(x, W_hh, b_ih, b_hh, Wh, Wl, bias, xT, Hb0, flags);
    rnn_kernel<<<NBLK, NTHR, 0, stream>>>(xT, W_ih, b_fc, W_fc, Wh, Wl, bias, Hb0, Hb1, flags, out);
}

// Round 3
// 1663.694 us; speedup vs baseline: 2.3121x; 1.2371x over previous
//
#include <hip/hip_runtime.h>
#include <stdint.h>

#define H 512
#define B_SZ 1024
#define T_WARM 256
#define NSTEPS 64
#define TOTAL_T (T_WARM + NSTEPS)

#define RPB 16          // rows per team
#define NTEAM 64        // B_SZ / RPB
#define NCG 4           // col groups (blocks per team)
#define NBLK 256        // NTEAM * NCG == CU count, 1 block/CU
#define NTHR 512        // 8 waves, each: 16 cols x K=512

// LDS h tile: 16 rows x 512 cols x 2B, row stride 1024 B, XOR-swizzled
// byte ^= (row&3)<<5  -> staging u32 writes 2-way (free), A b128 reads uniform
#define ROWB 1024

typedef __attribute__((ext_vector_type(8))) short bf16x8;
typedef __attribute__((ext_vector_type(4))) float f32x4;

static __device__ __forceinline__ ushort f2bf(float f) {
    uint32_t u = __builtin_bit_cast(uint32_t, f);
    u += 0x7FFFu + ((u >> 16) & 1u);
    return (ushort)(u >> 16);
}
static __device__ __forceinline__ float bf2f(ushort h) {
    uint32_t u = ((uint32_t)h) << 16;
    return __builtin_bit_cast(float, u);
}

__global__ void prep_kernel(const float* __restrict__ x,
                            const float* __restrict__ W_hh,
                            const float* __restrict__ b_ih,
                            const float* __restrict__ b_hh,
                            ushort* __restrict__ Wh, ushort* __restrict__ Wl,
                            float* __restrict__ bias, float* __restrict__ xT,
                            uint32_t* __restrict__ Hb0, uint32_t* __restrict__ flags) {
    int i = blockIdx.x * NTHR + threadIdx.x;     // [0, 524288)
    Hb0[i] = 0u;                                  // h(0) = 0 (packed hi|lo)
    if (i < 4096) flags[i] = 0u;                  // per-(team,cg,half,slot) step counters
    if (i < H * H) {
        float w = W_hh[i];
        ushort hi = f2bf(w);
        Wh[i] = hi;
        Wl[i] = f2bf(w - bf2f(hi));
    }
    if (i < B_SZ * T_WARM) {
        int b = i & (B_SZ - 1), t = i >> 10;
        xT[t * B_SZ + b] = x[b * T_WARM + t];
    }
    if (i < H) bias[i] = b_ih[i] + b_hh[i];
}

// R0 structure (8 symmetric waves, 16 cols x K=512 each, team-of-4 same-XCD
// h broadcast) with: swizzled conflict-free LDS, y fused from A-frags (no
// serial y phase), no tr scratch, per-wave flags, ONE barrier per step.
__global__ __launch_bounds__(NTHR, 1)
void rnn_kernel(const float* __restrict__ xT,
                const float* __restrict__ W_ih,
                const float* __restrict__ b_fc_p,
                const float* __restrict__ W_fc,
                const ushort* __restrict__ Wh_g,
                const ushort* __restrict__ Wl_g,
                const float* __restrict__ bias_g,
                uint32_t* __restrict__ Hb0, uint32_t* __restrict__ Hb1,
                uint32_t* __restrict__ flags,
                float* __restrict__ out) {
    __shared__ __align__(16) ushort h_hi[2][RPB * 512];   // ping-pong hi, 16 KB each
    __shared__ __align__(16) ushort h_lo[2][RPB * 512];   // ping-pong lo
    __shared__ __align__(16) float  w_fc_s[H];

    const int tid  = threadIdx.x;
    const int bid  = blockIdx.x;
    const int team = bid & (NTEAM - 1);   // blocks {team,+64,+128,+192}: same XCD
    const int cg   = bid >> 6;            // 0..3
    const int row0 = team * RPB;
    const int col0 = cg * 128;

    const int lane = tid & 63;
    const int wv   = tid >> 6;            // 0..7: 16-col tile, also staged 64-col slice
    const int n    = lane & 15, q = lane >> 4;

    w_fc_s[tid] = W_fc[tid];

    // ---- weights register-resident: wave's 16 cols x K=512, hi+lo = 128 VGPR ----
    bf16x8 Bh[16], Bl[16];
    {
        const ushort* wh = Wh_g + (col0 + wv * 16 + n) * H + q * 8;
        const ushort* wl = Wl_g + (col0 + wv * 16 + n) * H + q * 8;
        #pragma unroll
        for (int kt = 0; kt < 16; ++kt) {
            Bh[kt] = *(const bf16x8*)(wh + kt * 32);
            Bl[kt] = *(const bf16x8*)(wl + kt * 32);
        }
    }
    const float wi  = W_ih[col0 + wv * 16 + n];
    const float bj  = bias_g[col0 + wv * 16 + n];
    const float bfc = b_fc_p[0];

    // flags: [team][cg][half][slot]; producer wave wv -> (cg, wv>>2, wv&3)
    uint32_t* const myflag =
        flags + (((team * NCG + cg) * 2 + (wv >> 2)) << 2) + (wv & 3);
    // consumer: slice s = wv covers global cols [64s,+64) from block p=s>>1 half s&1
    const uint64_t* const pollp =
        (const uint64_t*)(flags + (((team * NCG + (wv >> 1)) * 2 + (wv & 1)) << 2));

    char* const hb0c = (char*)h_hi[0]; char* const hb1c = (char*)h_hi[1];
    char* const lb0c = (char*)h_lo[0]; char* const lb1c = (char*)h_lo[1];

    for (int t = 0; t < TOTAL_T; ++t) {
        const int pp = t & 1;
        const bool roll = (t >= T_WARM);

        f32x4 xq = {0.f, 0.f, 0.f, 0.f};
        if (!roll) xq = *(const f32x4*)(xT + t * B_SZ + row0 + q * 4);

        // ---- stage slice s=wv: poll 4 producer-wave flags, load, unpack ----
        if (t > 0) {
            const uint32_t need = (uint32_t)t;
            while (true) {
                uint64_t f0 = __hip_atomic_load(pollp,     __ATOMIC_RELAXED, __HIP_MEMORY_SCOPE_AGENT);
                uint64_t f1 = __hip_atomic_load(pollp + 1, __ATOMIC_RELAXED, __HIP_MEMORY_SCOPE_AGENT);
                if ((uint32_t)f0 >= need && (uint32_t)(f0 >> 32) >= need &&
                    (uint32_t)f1 >= need && (uint32_t)(f1 >> 32) >= need) break;
                __builtin_amdgcn_s_sleep(1);
            }
        }
        {
            const uint64_t* src = (const uint64_t*)((t & 1) ? Hb1 : Hb0);
            uint64_t tmp[8];
            #pragma unroll
            for (int it = 0; it < 8; ++it) {
                int idx = it * 64 + lane;            // r = idx>>5, c = idx&31
                int r = idx >> 5, c = idx & 31;
                tmp[it] = __hip_atomic_load(src + ((row0 + r) * 256 + wv * 32 + c),
                                            __ATOMIC_RELAXED, __HIP_MEMORY_SCOPE_AGENT);
            }
            char* hb = pp ? hb1c : hb0c;
            char* lb = pp ? lb1c : lb0c;
            #pragma unroll
            for (int it = 0; it < 8; ++it) {
                int idx = it * 64 + lane;
                int r = idx >> 5, c = idx & 31;
                int byte = (r * ROWB + wv * 128 + c * 4) ^ ((r & 3) << 5);
                uint64_t u = tmp[it];
                uint32_t w0 = (uint32_t)u, w1 = (uint32_t)(u >> 32);
                *(uint32_t*)(hb + byte) = (w0 >> 16) | (w1 & 0xFFFF0000u);
                *(uint32_t*)(lb + byte) = (w0 & 0xFFFFu) | (w1 << 16);
            }
        }
        __syncthreads();   // E: the only barrier per step

        // ---- MFMA (+ fused y during rollout) over K=512 ----
        const char* ha = (pp ? hb1c : hb0c);
        const char* la = (pp ? lb1c : lb0c);
        const int aoffs = n * ROWB + q * 16;
        const int aswz  = (n & 3) << 5;
        f32x4 a0 = {0.f, 0.f, 0.f, 0.f}, a1 = {0.f, 0.f, 0.f, 0.f};
        float yp = 0.f;

        if (!roll) {
            #pragma unroll
            for (int kt = 0; kt < 16; kt += 2) {
                const int b0 = (aoffs + kt * 64) ^ aswz;
                const int b1 = (aoffs + kt * 64 + 64) ^ aswz;
                bf16x8 ah0 = *(const bf16x8*)(ha + b0);
                bf16x8 al0 = *(const bf16x8*)(la + b0);
                bf16x8 ah1 = *(const bf16x8*)(ha + b1);
                bf16x8 al1 = *(const bf16x8*)(la + b1);
                a0 = __builtin_amdgcn_mfma_f32_16x16x32_bf16(ah0, Bh[kt],     a0, 0, 0, 0);
                a1 = __builtin_amdgcn_mfma_f32_16x16x32_bf16(ah1, Bh[kt + 1], a1, 0, 0, 0);
                a0 = __builtin_amdgcn_mfma_f32_16x16x32_bf16(al0, Bh[kt],     a0, 0, 0, 0);
                a1 = __builtin_amdgcn_mfma_f32_16x16x32_bf16(al1, Bh[kt + 1], a1, 0, 0, 0);
                a0 = __builtin_amdgcn_mfma_f32_16x16x32_bf16(ah0, Bl[kt],     a0, 0, 0, 0);
                a1 = __builtin_amdgcn_mfma_f32_16x16x32_bf16(ah1, Bl[kt + 1], a1, 0, 0, 0);
            }
        } else {
            #pragma unroll
            for (int kt = 0; kt < 16; kt += 2) {
                const int b0 = (aoffs + kt * 64) ^ aswz;
                const int b1 = (aoffs + kt * 64 + 64) ^ aswz;
                bf16x8 ah0 = *(const bf16x8*)(ha + b0);
                bf16x8 al0 = *(const bf16x8*)(la + b0);
                bf16x8 ah1 = *(const bf16x8*)(ha + b1);
                bf16x8 al1 = *(const bf16x8*)(la + b1);
                a0 = __builtin_amdgcn_mfma_f32_16x16x32_bf16(ah0, Bh[kt],     a0, 0, 0, 0);
                a1 = __builtin_amdgcn_mfma_f32_16x16x32_bf16(ah1, Bh[kt + 1], a1, 0, 0, 0);
                a0 = __builtin_amdgcn_mfma_f32_16x16x32_bf16(al0, Bh[kt],     a0, 0, 0, 0);
                a1 = __builtin_amdgcn_mfma_f32_16x16x32_bf16(al1, Bh[kt + 1], a1, 0, 0, 0);
                a0 = __builtin_amdgcn_mfma_f32_16x16x32_bf16(ah0, Bl[kt],     a0, 0, 0, 0);
                a1 = __builtin_amdgcn_mfma_f32_16x16x32_bf16(ah1, Bl[kt + 1], a1, 0, 0, 0);
                // y-partial: this lane's cols (q*8+j + 32*kt'), wfc via LDS broadcast
                #pragma unroll
                for (int u = 0; u < 2; ++u) {
                    const bf16x8 ah = u ? ah1 : ah0;
                    const bf16x8 al = u ? al1 : al0;
                    const float* wf = &w_fc_s[(kt + u) * 32 + q * 8];
                    f32x4 w0 = *(const f32x4*)wf;
                    f32x4 w1 = *(const f32x4*)(wf + 4);
                    #pragma unroll
                    for (int j = 0; j < 4; ++j) {
                        yp += bf2f((ushort)ah[j]) * w0[j] + bf2f((ushort)al[j]) * w0[j];
                        yp += bf2f((ushort)ah[j + 4]) * w1[j] + bf2f((ushort)al[j + 4]) * w1[j];
                    }
                }
            }
        }

        // ---- y reduce + out write (roll) ----
        float yfin = 0.f;
        if (roll) {
            yp += __shfl_xor(yp, 16);
            yp += __shfl_xor(yp, 32);          // all lanes: y for row n
            yfin = yp + bfc;
            if (cg == 0 && wv == 0 && lane < 16)
                out[(row0 + lane) * NSTEPS + (t - T_WARM)] = yfin;
        }

        // ---- epilogue: v = acc + s*w_in + bias, relu, split, publish ----
        uint32_t* hbn = (t & 1) ? Hb0 : Hb1;
        #pragma unroll
        for (int i = 0; i < 4; ++i) {
            const int m = q * 4 + i;           // C/D: row = quad*4+reg, col = n
            const float sv = roll ? __shfl(yfin, m) : xq[i];
            float v = a0[i] + a1[i] + sv * wi + bj;
            v = fmaxf(v, 0.f);
            const ushort hb16 = f2bf(v);
            const ushort lb16 = f2bf(v - bf2f(hb16));
            const uint32_t pk = ((uint32_t)hb16 << 16) | lb16;
            __hip_atomic_store(hbn + (row0 + m) * H + col0 + wv * 16 + n, pk,
                               __ATOMIC_RELAXED, __HIP_MEMORY_SCOPE_AGENT);
        }
        asm volatile("s_waitcnt vmcnt(0)" ::: "memory");
        if (lane == 0)
            __hip_atomic_store(myflag, (uint32_t)(t + 1),
                               __ATOMIC_RELAXED, __HIP_MEMORY_SCOPE_AGENT);
    }
}

extern "C" void kernel_launch(void* const* d_in, const int* in_sizes, int n_in,
                              void* d_out, int out_size, void* d_ws, size_t ws_size,
                              hipStream_t stream) {
    const float* x    = (const float*)d_in[0];
    const float* W_ih = (const float*)d_in[1];
    const float* W_hh = (const float*)d_in[2];
    const float* b_ih = (const float*)d_in[3];
    const float* b_hh = (const float*)d_in[4];
    const float* W_fc = (const float*)d_in[5];
    const float* b_fc = (const float*)d_in[6];
    float* out = (float*)d_out;

    // ws carve (bytes): Wh 512K | Wl 512K | bias 4K | xT 1M | Hb0 2M | Hb1 2M | flags 16K
    uint8_t* w = (uint8_t*)d_ws;
    ushort*   Wh    = (ushort*)(w);
    ushort*   Wl    = (ushort*)(w + 524288);
    float*    bias  = (float*)(w + 1048576);
    float*    xT    = (float*)(w + 1052672);
    uint32_t* Hb0   = (uint32_t*)(w + 2101248);
    uint32_t* Hb1   = (uint32_t*)(w + 4198400);
    uint32_t* flags = (uint32_t*)(w + 6295552);

    prep_kernel<<<1024, NTHR, 0, stream>>>(x, W_hh, b_ih, b_hh, Wh, Wl, bias, xT, Hb0, flags);
    rnn_kernel<<<NBLK, NTHR, 0, stream>>>(xT, W_ih, b_fc, W_fc, Wh, Wl, bias, Hb0, Hb1, flags, out);
}